// Round 3
// baseline (220.780 us; speedup 1.0000x reference)
//
#include <hip/hip_runtime.h>

// ChannelKiller: out[b,c,t] = x[b,c,t] * (c==0 ? 1.0f : 0.5f)
// Shapes: B=16, C=8, T=262144 (fp32) -> n = 33,554,432 floats, n4 = 8,388,608 float4s.
// T/4 = 65536 float4s per (b,c) channel-run.
//
// Memory-bound: 268 MB total traffic, floor ~42.6 us @ 6.3 TB/s achievable copy BW.
//
// Round 3: deepen per-thread batch to 8 independent float4 loads (MLP=8,
// 128 B/lane) before any store; 4096 blocks (half the launch/ramp overhead).
// Keep nontemporal hints (round 2: -7.7 us, reads+writes stream past L2/L3).
// Channel remains block-uniform: 2048 float4s per block, 32 blocks per
// channel-run of 65536 -> c = (blockIdx.x >> 5) & 7, scale in SGPR.

using f32x4 = __attribute__((ext_vector_type(4))) float;

__global__ void __launch_bounds__(256)
channel_killer_kernel(const f32x4* __restrict__ x, f32x4* __restrict__ out) {
    const int base = blockIdx.x * 2048 + threadIdx.x;
    // Block-uniform scale: 32 blocks per channel-run of 65536 float4s.
    const float s = ((blockIdx.x >> 5) & 7) == 0 ? 1.0f : 0.5f;

    f32x4 v0 = __builtin_nontemporal_load(&x[base]);
    f32x4 v1 = __builtin_nontemporal_load(&x[base + 256]);
    f32x4 v2 = __builtin_nontemporal_load(&x[base + 512]);
    f32x4 v3 = __builtin_nontemporal_load(&x[base + 768]);
    f32x4 v4 = __builtin_nontemporal_load(&x[base + 1024]);
    f32x4 v5 = __builtin_nontemporal_load(&x[base + 1280]);
    f32x4 v6 = __builtin_nontemporal_load(&x[base + 1536]);
    f32x4 v7 = __builtin_nontemporal_load(&x[base + 1792]);

    v0 *= s; v1 *= s; v2 *= s; v3 *= s;
    v4 *= s; v5 *= s; v6 *= s; v7 *= s;

    __builtin_nontemporal_store(v0, &out[base]);
    __builtin_nontemporal_store(v1, &out[base + 256]);
    __builtin_nontemporal_store(v2, &out[base + 512]);
    __builtin_nontemporal_store(v3, &out[base + 768]);
    __builtin_nontemporal_store(v4, &out[base + 1024]);
    __builtin_nontemporal_store(v5, &out[base + 1280]);
    __builtin_nontemporal_store(v6, &out[base + 1536]);
    __builtin_nontemporal_store(v7, &out[base + 1792]);
}

extern "C" void kernel_launch(void* const* d_in, const int* in_sizes, int n_in,
                              void* d_out, int out_size, void* d_ws, size_t ws_size,
                              hipStream_t stream) {
    const f32x4* x = (const f32x4*)d_in[0];
    f32x4* out = (f32x4*)d_out;
    const int n = in_sizes[0];          // 33,554,432 floats
    const int n4 = n >> 2;              // 8,388,608 float4s

    const int block = 256;
    const int grid = n4 >> 11;          // 2048 float4s per block -> 4096 blocks (exact)
    channel_killer_kernel<<<grid, block, 0, stream>>>(x, out);
}